// Round 4
// baseline (272.862 us; speedup 1.0000x reference)
//
#include <hip/hip_runtime.h>

#define SEQ  2048
#define DIM  1024
#define NTOK 8192   // 4*SEQ
#define NQKV 3072

typedef __attribute__((ext_vector_type(8))) __bf16 bf16x8;
typedef __attribute__((ext_vector_type(4))) float  f32x4;

__device__ __forceinline__ unsigned short f2bf(float f) {
    unsigned int u = __float_as_uint(f);
    u += 0x7fffu + ((u >> 16) & 1u);          // round-to-nearest-even
    return (unsigned short)(u >> 16);
}

__device__ __forceinline__ float bfu2f(unsigned int lo16) {
    return __uint_as_float(lo16 << 16);
}

__device__ __forceinline__ void load_lds_128(const unsigned short* g, unsigned short* l) {
    __builtin_amdgcn_global_load_lds(
        (const __attribute__((address_space(1))) void*)g,
        (__attribute__((address_space(3))) void*)l, 16, 0, 0);
}

#define BAR() asm volatile("s_barrier" ::: "memory")

// ---------------------------------------------------------------------------
// NT GEMM, bf16 MFMA 16x16x32.  BM x 256 block (BM = MB*128), BK=64,
// 8 waves as 2M x 4N (per-wave (BM/2) x 64).  2-buffer LDS, distance-1
// prefetch issued at ITER START (so the iter-end vmcnt(0) drains ~2800-cyc-old
// loads = free), ONE barrier per K-tile.
//
// Per iter: stage(t+1) -> buf^1 | 24(MB=2)/16(MB=1) ds_read_b128 up front |
//           4 MFMA clusters (setprio-wrapped) | lgkmcnt(0)+vmcnt(0) | barrier.
// Compiler's in-order lgkm counting starts Ph0 at lgkmcnt(8) while a_hi
// reads fly under Ph0+Ph1 (proven round 3).
//
// WAR: stage(t+1) targets the buffer whose readers drained at the previous
// iter's lgkmcnt(0)-before-barrier; stage is issued after that barrier.
// Visibility: reads of tile t gated by prior iter's vmcnt(0)+barrier.
//
// LDS rows 128B (full bank period); chunk slot c of row r holds global chunk
// g = c ^ (r&7) -> fragment ds_read_b128 2-way (free); SQ_LDS_BANK_CONFLICT==0
// verified.  global_load_lds dest linear; XOR applied to global source.
//
// MODE 0: fused QKV epilogue (q,k bf16 + bias; v transposed into vt + bias)
// MODE 1: fp32 C = acc * inv_rs[row]   (normalized P.V output)
// MODE 2: bf16 C = exp(acc * alpha)    (unnormalized softmax numerator)
// ---------------------------------------------------------------------------
template <int MODE, int MB>
__global__ __launch_bounds__(512, 2)
void gemm2(const unsigned short* __restrict__ A, const unsigned short* __restrict__ B,
           void* __restrict__ Cv,
           const float* __restrict__ b0v, const float* __restrict__ b1v,
           const float* __restrict__ b2v, unsigned short* __restrict__ vt,
           const float* __restrict__ inv_rs,
           int K, int lda, int ldb, int ldc,
           long sA, long sB, long sC, float alpha)
{
    constexpr int BM = MB * 128;
    constexpr int AT = BM * 64;                 // elems per A buffer
    constexpr int BT = 256 * 64;                // elems per B buffer (BN=256)
    constexpr int MH = MB * 2;                  // mf per half
    __shared__ __align__(16) unsigned short As[2 * AT];   // 64/32 KB
    __shared__ __align__(16) unsigned short Bs[2 * BT];   // 64 KB

    const int tid  = threadIdx.x;               // 512 threads = 8 waves
    const int wave = tid >> 6;
    const int lane = tid & 63;
    const int l4   = lane & 15;
    const int lh   = lane >> 4;
    const int wm   = wave >> 2;                 // 0..1  (M half)
    const int wn   = wave & 3;                  // 0..3  (N quarter)

    const int m0 = blockIdx.x * BM;
    const int n0 = blockIdx.y * 256;
    const int z  = blockIdx.z;
    A += (long)z * sA;
    B += (long)z * sB;

    // staging map: LDS pos s = tid + 512p -> row s>>3 (= r0+64p), slot s&7;
    // slot c holds global chunk g = c ^ (r&7); (r&7) p-invariant.
    const int r0 = tid >> 3;                    // 0..63
    const int gc = (tid & 7) ^ (r0 & 7);
    const unsigned short* Ag = A + (long)(m0 + r0) * lda + gc * 8;
    const unsigned short* Bg = B + (long)(n0 + r0) * ldb + gc * 8;
    unsigned short* Al = As + tid * 8;
    unsigned short* Bl = Bs + tid * 8;

    const int NT = K >> 6;                      // K-tiles of 64

    auto stage = [&](int t, int u) {
        const long kof = (long)t * 64;
#pragma unroll
        for (int p = 0; p < 2 * MB; ++p)
            load_lds_128(Ag + kof + (long)(64 * p) * lda, Al + u * AT + p * 4096);
#pragma unroll
        for (int p = 0; p < 4; ++p)
            load_lds_128(Bg + kof + (long)(64 * p) * ldb, Bl + u * BT + p * 4096);
    };

    // fragment lane offsets: A frag (mf,kk): row R = wm*(BM/2)+mf*16+l4,
    // chunk g = kk*4+lh, slot = g ^ (R&7) = g ^ (lane&7).
    const int aoff = (wm * (BM / 2) + l4) * 64;   // + mf*1024 + cs[kk]
    const int boff = (wn * 64 + l4) * 64;         // + nf*1024 + cs[kk]
    const int cs0  = ((0 + lh) ^ (lane & 7)) * 8;
    const int cs1  = ((4 + lh) ^ (lane & 7)) * 8;

    f32x4 acc[4 * MB][4] = {};
    bf16x8 alo[MH][2], ahi[MH][2], bfr[4][2];

    // ---- prologue ----
    stage(0, 0);
    asm volatile("s_waitcnt vmcnt(0)" ::: "memory");
    BAR();

    for (int t = 0; t < NT; ++t) {
        const int u = t & 1;
        const unsigned short* Ab = As + u * AT + aoff;
        const unsigned short* Bb = Bs + u * BT + boff;

        if (t + 1 < NT) stage(t + 1, u ^ 1);

        // ---- all fragment reads up front (in-order lgkm counting) ----
#pragma unroll
        for (int nf = 0; nf < 4; ++nf) {
            bfr[nf][0] = *(const bf16x8*)(Bb + nf * 1024 + cs0);
            bfr[nf][1] = *(const bf16x8*)(Bb + nf * 1024 + cs1);
        }
#pragma unroll
        for (int mf = 0; mf < MH; ++mf) {
            alo[mf][0] = *(const bf16x8*)(Ab + mf * 1024 + cs0);
            alo[mf][1] = *(const bf16x8*)(Ab + mf * 1024 + cs1);
        }
#pragma unroll
        for (int mf = 0; mf < MH; ++mf) {
            ahi[mf][0] = *(const bf16x8*)(Ab + (MH + mf) * 1024 + cs0);
            ahi[mf][1] = *(const bf16x8*)(Ab + (MH + mf) * 1024 + cs1);
        }

        // ---- Ph0: alo x nf0-1 ----
        __builtin_amdgcn_s_setprio(1);
#pragma unroll
        for (int mf = 0; mf < MH; ++mf)
#pragma unroll
            for (int nf = 0; nf < 2; ++nf)
#pragma unroll
                for (int kk = 0; kk < 2; ++kk)
                    acc[mf][nf] = __builtin_amdgcn_mfma_f32_16x16x32_bf16(
                        alo[mf][kk], bfr[nf][kk], acc[mf][nf], 0, 0, 0);
        __builtin_amdgcn_s_setprio(0);
        // ---- Ph1: alo x nf2-3 ----
        __builtin_amdgcn_s_setprio(1);
#pragma unroll
        for (int mf = 0; mf < MH; ++mf)
#pragma unroll
            for (int nf = 2; nf < 4; ++nf)
#pragma unroll
                for (int kk = 0; kk < 2; ++kk)
                    acc[mf][nf] = __builtin_amdgcn_mfma_f32_16x16x32_bf16(
                        alo[mf][kk], bfr[nf][kk], acc[mf][nf], 0, 0, 0);
        __builtin_amdgcn_s_setprio(0);
        // ---- Ph2: ahi x nf2-3 ----
        __builtin_amdgcn_s_setprio(1);
#pragma unroll
        for (int mf = 0; mf < MH; ++mf)
#pragma unroll
            for (int nf = 2; nf < 4; ++nf)
#pragma unroll
                for (int kk = 0; kk < 2; ++kk)
                    acc[MH + mf][nf] = __builtin_amdgcn_mfma_f32_16x16x32_bf16(
                        ahi[mf][kk], bfr[nf][kk], acc[MH + mf][nf], 0, 0, 0);
        __builtin_amdgcn_s_setprio(0);
        // ---- Ph3: ahi x nf0-1 ----
        __builtin_amdgcn_s_setprio(1);
#pragma unroll
        for (int mf = 0; mf < MH; ++mf)
#pragma unroll
            for (int nf = 0; nf < 2; ++nf)
#pragma unroll
                for (int kk = 0; kk < 2; ++kk)
                    acc[MH + mf][nf] = __builtin_amdgcn_mfma_f32_16x16x32_bf16(
                        ahi[mf][kk], bfr[nf][kk], acc[MH + mf][nf], 0, 0, 0);
        __builtin_amdgcn_s_setprio(0);

        asm volatile("s_waitcnt vmcnt(0) lgkmcnt(0)" ::: "memory");
        BAR();
    }

    // ---- epilogue ----
    // C/D 16x16x32: col = lane&15 (+nf*16), row = (lane>>4)*4 + reg (+mf*16)
    const int r0c = m0 + wm * (BM / 2) + lh * 4;
    const int c0c = n0 + wn * 64 + l4;

    if (MODE == 0) {
        if (n0 >= 2048) {
            // V columns -> vt[b][d][m] (+bias), packed 4-m ushort4 stores
#pragma unroll
            for (int nf = 0; nf < 4; ++nf) {
                const int d = c0c + nf * 16 - 2048;
                const float bias = b2v[d];
#pragma unroll
                for (int mf = 0; mf < 4 * MB; ++mf) {
                    const int row = r0c + mf * 16;
                    const int bb = row >> 11;
                    const int mm = row & 2047;
                    ushort4 u;
                    u.x = f2bf(acc[mf][nf][0] + bias);
                    u.y = f2bf(acc[mf][nf][1] + bias);
                    u.z = f2bf(acc[mf][nf][2] + bias);
                    u.w = f2bf(acc[mf][nf][3] + bias);
                    *(ushort4*)(vt + ((long)bb * DIM + d) * SEQ + mm) = u;
                }
            }
        } else {
            unsigned short* C16 = (unsigned short*)Cv;
#pragma unroll
            for (int nf = 0; nf < 4; ++nf) {
                const int col = c0c + nf * 16;
                const float bias = (col >= 1024) ? b1v[col - 1024] : b0v[col];
#pragma unroll
                for (int mf = 0; mf < 4 * MB; ++mf)
#pragma unroll
                    for (int r = 0; r < 4; ++r)
                        C16[(long)(r0c + mf * 16 + r) * ldc + col] =
                            f2bf(acc[mf][nf][r] + bias);
            }
        }
    } else if (MODE == 1) {
        float* C = (float*)Cv + (long)z * sC;
        const float* ir = inv_rs + (long)z * SEQ;
#pragma unroll
        for (int mf = 0; mf < 4 * MB; ++mf) {
            const int row = r0c + mf * 16;
            const float4 inv4 = *(const float4*)(ir + row);
#pragma unroll
            for (int nf = 0; nf < 4; ++nf) {
                const int col = c0c + nf * 16;
                C[(long)(row + 0) * ldc + col] = acc[mf][nf][0] * inv4.x;
                C[(long)(row + 1) * ldc + col] = acc[mf][nf][1] * inv4.y;
                C[(long)(row + 2) * ldc + col] = acc[mf][nf][2] * inv4.z;
                C[(long)(row + 3) * ldc + col] = acc[mf][nf][3] * inv4.w;
            }
        }
    } else {  // MODE 2: P = exp(acc * alpha), bf16, unnormalized
        unsigned short* C16 = (unsigned short*)Cv + (long)z * sC;
#pragma unroll
        for (int nf = 0; nf < 4; ++nf) {
            const int col = c0c + nf * 16;
#pragma unroll
            for (int mf = 0; mf < 4 * MB; ++mf)
#pragma unroll
                for (int r = 0; r < 4; ++r)
                    C16[(long)(r0c + mf * 16 + r) * ldc + col] =
                        f2bf(__expf(acc[mf][nf][r] * alpha));
        }
    }
}

// ---------------------------------------------------------------------------
__global__ __launch_bounds__(256)
void cvt_x(const float* __restrict__ src, unsigned short* __restrict__ dst, int n4)
{
    int i = blockIdx.x * 256 + threadIdx.x;
    if (i < n4) {
        float4 f = ((const float4*)src)[i];
        ushort4 u;
        u.x = f2bf(f.x); u.y = f2bf(f.y); u.z = f2bf(f.z); u.w = f2bf(f.w);
        ((ushort4*)dst)[i] = u;
    }
}

__global__ __launch_bounds__(256)
void cvt_w3(const float* __restrict__ Wq, const float* __restrict__ Wk,
            const float* __restrict__ Wv, unsigned short* __restrict__ dst)
{
    const int sel = blockIdx.y;
    const float* src = (sel == 0) ? Wq : ((sel == 1) ? Wk : Wv);
    const int i = blockIdx.x * 256 + threadIdx.x;
    float4 f = ((const float4*)src)[i];
    ushort4 u;
    u.x = f2bf(f.x); u.y = f2bf(f.y); u.z = f2bf(f.z); u.w = f2bf(f.w);
    ((ushort4*)(dst + (long)sel * DIM * DIM))[i] = u;
}

// ---------------------------------------------------------------------------
// inv_rs[row] = 1 / sum(P[row][:]) over 2048 bf16 values. 1 wave per row.
// ---------------------------------------------------------------------------
__global__ __launch_bounds__(256)
void rowsum_inv(const unsigned short* __restrict__ P, float* __restrict__ inv_rs)
{
    const int row  = blockIdx.x * 4 + (threadIdx.x >> 6);
    const int lane = threadIdx.x & 63;
    const unsigned short* pr = P + (long)row * SEQ;

    float s = 0.f;
#pragma unroll
    for (int it = 0; it < 4; ++it) {
        uint4 u = *(const uint4*)(pr + (it * 64 + lane) * 8);
        s += bfu2f(u.x & 0xffffu) + __uint_as_float(u.x & 0xffff0000u);
        s += bfu2f(u.y & 0xffffu) + __uint_as_float(u.y & 0xffff0000u);
        s += bfu2f(u.z & 0xffffu) + __uint_as_float(u.z & 0xffff0000u);
        s += bfu2f(u.w & 0xffffu) + __uint_as_float(u.w & 0xffff0000u);
    }
    for (int off = 32; off > 0; off >>= 1)
        s += __shfl_xor(s, off);
    if (lane == 0) inv_rs[row] = 1.0f / s;
}

// ---------------------------------------------------------------------------
extern "C" void kernel_launch(void* const* d_in, const int* in_sizes, int n_in,
                              void* d_out, int out_size, void* d_ws, size_t ws_size,
                              hipStream_t stream)
{
    const float* x  = (const float*)d_in[0];
    const float* Wq = (const float*)d_in[1];
    const float* bq = (const float*)d_in[2];
    const float* Wk = (const float*)d_in[3];
    const float* bk = (const float*)d_in[4];
    const float* Wv = (const float*)d_in[5];
    const float* bv = (const float*)d_in[6];
    float* out = (float*)d_out;

    // Workspace layout (>=160MB + 32KB):
    //  [0,16MB):    xb bf16 [8192][1024]
    //  [16,22MB):   Wb bf16 [3][1024][1024]
    //  [64,112MB):  qkv bf16 [8192][3072]  (V cols never written; vt instead)
    //  [112,128MB): vt  bf16 [4][1024][2048]
    //  [128,160MB): P   bf16 [4][2048][2048]  (unnormalized exp)
    //  [160MB,+32KB): inv_rs fp32 [8192]
    char* ws = (char*)d_ws;
    unsigned short* xb   = (unsigned short*)ws;
    unsigned short* Wb   = (unsigned short*)(ws + 16u * 1024 * 1024);
    unsigned short* qkv  = (unsigned short*)(ws + 64u * 1024 * 1024);
    unsigned short* vt   = (unsigned short*)(ws + 112u * 1024 * 1024);
    unsigned short* P    = (unsigned short*)(ws + 128u * 1024 * 1024);
    float*          irs  = (float*)(ws + 160u * 1024 * 1024);

    const float scale = 0.03125f;   // 1/sqrt(1024)
    dim3 blk(256);
    dim3 blk512(512);

    // 1) converts
    cvt_x<<<NTOK * DIM / 4 / 256, blk, 0, stream>>>(x, xb, NTOK * DIM / 4);
    cvt_w3<<<dim3(DIM * DIM / 4 / 256, 3), blk, 0, stream>>>(Wq, Wk, Wv, Wb);

    // 2) fused QKV projection, 256x256 tiles -> 32*12 = 384 blocks (75% fill)
    gemm2<0, 2><<<dim3(NTOK / 256, NQKV / 256), blk512, 0, stream>>>(
        xb, Wb, qkv, bq, bk, bv, vt, nullptr,
        DIM, DIM, DIM, NQKV, 0, 0, 0, 1.0f);

    // 3) P[b] = exp(q[b].k[b]^T * scale), 256x256 tiles -> 8*8*4 = 256 blocks
    gemm2<2, 2><<<dim3(SEQ / 256, SEQ / 256, 4), blk512, 0, stream>>>(
        qkv, qkv + 1024, P, nullptr, nullptr, nullptr, nullptr, nullptr,
        DIM, NQKV, NQKV, SEQ,
        (long)SEQ * NQKV, (long)SEQ * NQKV, (long)SEQ * SEQ, scale);

    // 4) inv_rs = 1 / rowsum(P)
    rowsum_inv<<<NTOK / 4, blk, 0, stream>>>(P, irs);

    // 5) out[b] = (P[b].vt[b]^T) * inv_rs, 128x256 tiles -> 16*4*4 = 256 blocks
    gemm2<1, 1><<<dim3(SEQ / 128, DIM / 256, 4), blk512, 0, stream>>>(
        P, vt, out, nullptr, nullptr, nullptr, nullptr, irs,
        SEQ, SEQ, SEQ, DIM,
        (long)SEQ * SEQ, (long)DIM * SEQ, (long)SEQ * DIM, 1.0f);
}

// Round 5
// 252.055 us; speedup vs baseline: 1.0825x; 1.0825x over previous
//
#include <hip/hip_runtime.h>

#define SEQ  2048
#define DIM  1024
#define NTOK 8192   // 4*SEQ
#define NQKV 3072

typedef __attribute__((ext_vector_type(8))) __bf16 bf16x8;
typedef __attribute__((ext_vector_type(4))) float  f32x4;

__device__ __forceinline__ unsigned short f2bf(float f) {
    unsigned int u = __float_as_uint(f);
    u += 0x7fffu + ((u >> 16) & 1u);          // round-to-nearest-even
    return (unsigned short)(u >> 16);
}

__device__ __forceinline__ float bfu2f(unsigned int lo16) {
    return __uint_as_float(lo16 << 16);
}

__device__ __forceinline__ void load_lds_128(const unsigned short* g, unsigned short* l) {
    __builtin_amdgcn_global_load_lds(
        (const __attribute__((address_space(1))) void*)g,
        (__attribute__((address_space(3))) void*)l, 16, 0, 0);
}

#define BAR() asm volatile("s_barrier" ::: "memory")

// one 16-MFMA quadrant cluster: A frags AFR[0..3][kk], B frags bfr[NB..NB+1][kk]
#define CLUSTER(AFR, NB, MBASE)                                            \
    do {                                                                   \
        __builtin_amdgcn_s_setprio(1);                                     \
        _Pragma("unroll")                                                  \
        for (int mf = 0; mf < 4; ++mf)                                     \
            _Pragma("unroll")                                              \
            for (int nn = 0; nn < 2; ++nn)                                 \
                _Pragma("unroll")                                          \
                for (int kk = 0; kk < 2; ++kk)                             \
                    acc[(MBASE) + mf][(NB) + nn] =                         \
                        __builtin_amdgcn_mfma_f32_16x16x32_bf16(           \
                            AFR[mf][kk], bfr[(NB) + nn][kk],               \
                            acc[(MBASE) + mf][(NB) + nn], 0, 0, 0);        \
        __builtin_amdgcn_s_setprio(0);                                     \
    } while (0)

// ---------------------------------------------------------------------------
// NT GEMM, bf16 MFMA 16x16x32.  (MB*128) x 256 block, BK=64, 8 waves as
// 2M x 4N (per-wave (MB*64) x 64).  2-buffer LDS, distance-1 prefetch,
// ONE barrier per K-step, phase-split reads to keep <=16 live fragments
// (round-4 lesson: 24 live frags + 128-AGPR acc hit the 256/wave cap and
// the compiler destroyed the schedule).
//
// Per iter (MB=2):
//   head: rd b01(4), a0-3(8), b23(4)   -> P0 starts at counted lgkm(4)
//   stage(t+1 -> buf^1)  (8 gloads, early: vmcnt(0) at iter end is stale=free)
//   P0 = mf0-3 x nf0-1 | rd a4-7(8) | P1 = mf0-3 x nf2-3 (lgkm(8))
//   P2 = mf4-7 x nf2-3 (lgkm(0)) | vmcnt(0)+lgkmcnt(0) | BARRIER
//   P3 = mf4-7 x nf0-1  <- regs only, AFTER the barrier: covers next iter's
//        16 head reads + stage issue (cross-iteration overlap round 3 lacked)
// MB=1: P0 = mf0-3 x nf0-1 | drain | BARRIER | P1 = mf0-3 x nf2-3.
//
// WAR: reads from buf u all drained by explicit lgkmcnt(0) BEFORE the
// barrier; next iter's stages (targeting u) issue after it.  Visibility:
// buf u^1 staged this iter, vmcnt(0) before the barrier.
//
// LDS rows 128B (full bank period); chunk slot c of row r holds global chunk
// g = c ^ (r&7) -> fragment ds_read_b128 2-way (free); SQ_LDS_BANK_CONFLICT==0
// verified rounds 2-4.  global_load_lds dest linear; XOR on global source.
//
// MODE 0: fused QKV epilogue (q,k bf16 + bias; v transposed into vt + bias)
// MODE 1: fp32 C = acc * inv_rs[row]   (normalized P.V output)
// MODE 2: bf16 C = exp(acc * alpha)    (unnormalized softmax numerator)
// ---------------------------------------------------------------------------
template <int MODE, int MB>
__global__ __launch_bounds__(512, 2)
void gemm2(const unsigned short* __restrict__ A, const unsigned short* __restrict__ B,
           void* __restrict__ Cv,
           const float* __restrict__ b0v, const float* __restrict__ b1v,
           const float* __restrict__ b2v, unsigned short* __restrict__ vt,
           const float* __restrict__ inv_rs,
           int K, int lda, int ldb, int ldc,
           long sA, long sB, long sC, float alpha)
{
    constexpr int BM = MB * 128;
    constexpr int AT = BM * 64;                 // elems per A buffer (16/32 KB)
    constexpr int BT = 256 * 64;                // elems per B buffer (32 KB)
    __shared__ __align__(16) unsigned short As[2 * AT];
    __shared__ __align__(16) unsigned short Bs[2 * BT];

    const int tid  = threadIdx.x;               // 512 threads = 8 waves
    const int wave = tid >> 6;
    const int lane = tid & 63;
    const int l4   = lane & 15;
    const int lh   = lane >> 4;
    const int wm   = wave >> 2;                 // 0..1  (M half)
    const int wn   = wave & 3;                  // 0..3  (N quarter)

    const int m0 = blockIdx.x * BM;
    const int n0 = blockIdx.y * 256;
    const int z  = blockIdx.z;
    A += (long)z * sA;
    B += (long)z * sB;

    // staging map: LDS pos s = tid + 512p -> row s>>3 (= r0+64p), slot s&7;
    // slot c holds global chunk g = c ^ (r&7); (r&7) p-invariant.
    const int r0 = tid >> 3;                    // 0..63
    const int gc = (tid & 7) ^ (r0 & 7);
    const unsigned short* Ag = A + (long)(m0 + r0) * lda + gc * 8;
    const unsigned short* Bg = B + (long)(n0 + r0) * ldb + gc * 8;
    unsigned short* Al = As + tid * 8;
    unsigned short* Bl = Bs + tid * 8;

    const int NT = K >> 6;                      // K-steps of 64

    auto stage = [&](int t, int u) {
        const long kof = (long)t * 64;
#pragma unroll
        for (int p = 0; p < 2 * MB; ++p)
            load_lds_128(Ag + kof + (long)(64 * p) * lda, Al + u * AT + p * 4096);
#pragma unroll
        for (int p = 0; p < 4; ++p)
            load_lds_128(Bg + kof + (long)(64 * p) * ldb, Bl + u * BT + p * 4096);
    };

    // fragment lane offsets: A frag (mf,kk): row R = wm*(BM/2)+mf*16+l4,
    // chunk g = kk*4+lh, slot = g ^ (R&7) = g ^ (lane&7).
    const int aoff = (wm * (BM / 2) + l4) * 64;   // + mf*1024 + cs[kk]
    const int boff = (wn * 64 + l4) * 64;         // + nf*1024 + cs[kk]
    const int cs0  = ((0 + lh) ^ (lane & 7)) * 8;
    const int cs1  = ((4 + lh) ^ (lane & 7)) * 8;

    f32x4 acc[4 * MB][4] = {};
    bf16x8 bfr[4][2], alo[4][2], ahi[4][2];

    // ---- prologue ----
    stage(0, 0);
    asm volatile("s_waitcnt vmcnt(0)" ::: "memory");
    BAR();

    for (int t = 0; t < NT; ++t) {
        const int u = t & 1;
        const unsigned short* Ab = As + u * AT + aoff;
        const unsigned short* Bb = Bs + u * BT + boff;

        // ---- head reads: b01, a0-3, b23 (issue order -> counted waits) ----
#pragma unroll
        for (int nn = 0; nn < 2; ++nn) {
            bfr[nn][0] = *(const bf16x8*)(Bb + nn * 1024 + cs0);
            bfr[nn][1] = *(const bf16x8*)(Bb + nn * 1024 + cs1);
        }
#pragma unroll
        for (int mf = 0; mf < 4; ++mf) {
            alo[mf][0] = *(const bf16x8*)(Ab + mf * 1024 + cs0);
            alo[mf][1] = *(const bf16x8*)(Ab + mf * 1024 + cs1);
        }
#pragma unroll
        for (int nn = 2; nn < 4; ++nn) {
            bfr[nn][0] = *(const bf16x8*)(Bb + nn * 1024 + cs0);
            bfr[nn][1] = *(const bf16x8*)(Bb + nn * 1024 + cs1);
        }
        if (t + 1 < NT) stage(t + 1, u ^ 1);

        if constexpr (MB == 2) {
            CLUSTER(alo, 0, 0);                 // P0 (starts at lgkm(4))
#pragma unroll
            for (int mf = 0; mf < 4; ++mf) {    // mid reads under P0
                ahi[mf][0] = *(const bf16x8*)(Ab + (4 + mf) * 1024 + cs0);
                ahi[mf][1] = *(const bf16x8*)(Ab + (4 + mf) * 1024 + cs1);
            }
            CLUSTER(alo, 2, 0);                 // P1 (lgkm(8): ahi in flight)
            CLUSTER(ahi, 2, 4);                 // P2 (lgkm(0))
            asm volatile("s_waitcnt vmcnt(0) lgkmcnt(0)" ::: "memory");
            BAR();
            CLUSTER(ahi, 0, 4);                 // P3: regs-only, covers next head
        } else {
            CLUSTER(alo, 0, 0);                 // P0
            asm volatile("s_waitcnt vmcnt(0) lgkmcnt(0)" ::: "memory");
            BAR();
            CLUSTER(alo, 2, 0);                 // P1: regs-only, covers next head
        }
    }

    // ---- epilogue ----
    // C/D 16x16x32: col = lane&15 (+nf*16), row = (lane>>4)*4 + reg (+mf*16)
    const int r0c = m0 + wm * (BM / 2) + lh * 4;
    const int c0c = n0 + wn * 64 + l4;

    if (MODE == 0) {
        if (n0 >= 2048) {
            // V columns -> vt[b][d][m] (+bias), packed 4-m ushort4 stores
#pragma unroll
            for (int nf = 0; nf < 4; ++nf) {
                const int d = c0c + nf * 16 - 2048;
                const float bias = b2v[d];
#pragma unroll
                for (int mf = 0; mf < 4 * MB; ++mf) {
                    const int row = r0c + mf * 16;
                    const int bb = row >> 11;
                    const int mm = row & 2047;
                    ushort4 u;
                    u.x = f2bf(acc[mf][nf][0] + bias);
                    u.y = f2bf(acc[mf][nf][1] + bias);
                    u.z = f2bf(acc[mf][nf][2] + bias);
                    u.w = f2bf(acc[mf][nf][3] + bias);
                    *(ushort4*)(vt + ((long)bb * DIM + d) * SEQ + mm) = u;
                }
            }
        } else {
            unsigned short* C16 = (unsigned short*)Cv;
#pragma unroll
            for (int nf = 0; nf < 4; ++nf) {
                const int col = c0c + nf * 16;
                const float bias = (col >= 1024) ? b1v[col - 1024] : b0v[col];
#pragma unroll
                for (int mf = 0; mf < 4 * MB; ++mf)
#pragma unroll
                    for (int r = 0; r < 4; ++r)
                        C16[(long)(r0c + mf * 16 + r) * ldc + col] =
                            f2bf(acc[mf][nf][r] + bias);
            }
        }
    } else if (MODE == 1) {
        float* C = (float*)Cv + (long)z * sC;
        const float* ir = inv_rs + (long)z * SEQ;
#pragma unroll
        for (int mf = 0; mf < 4 * MB; ++mf) {
            const int row = r0c + mf * 16;
            const float4 inv4 = *(const float4*)(ir + row);
#pragma unroll
            for (int nf = 0; nf < 4; ++nf) {
                const int col = c0c + nf * 16;
                C[(long)(row + 0) * ldc + col] = acc[mf][nf][0] * inv4.x;
                C[(long)(row + 1) * ldc + col] = acc[mf][nf][1] * inv4.y;
                C[(long)(row + 2) * ldc + col] = acc[mf][nf][2] * inv4.z;
                C[(long)(row + 3) * ldc + col] = acc[mf][nf][3] * inv4.w;
            }
        }
    } else {  // MODE 2: P = exp(acc * alpha), bf16, unnormalized
        unsigned short* C16 = (unsigned short*)Cv + (long)z * sC;
#pragma unroll
        for (int nf = 0; nf < 4; ++nf) {
            const int col = c0c + nf * 16;
#pragma unroll
            for (int mf = 0; mf < 4 * MB; ++mf)
#pragma unroll
                for (int r = 0; r < 4; ++r)
                    C16[(long)(r0c + mf * 16 + r) * ldc + col] =
                        f2bf(__expf(acc[mf][nf][r] * alpha));
        }
    }
}

// ---------------------------------------------------------------------------
__global__ __launch_bounds__(256)
void cvt_x(const float* __restrict__ src, unsigned short* __restrict__ dst, int n4)
{
    int i = blockIdx.x * 256 + threadIdx.x;
    if (i < n4) {
        float4 f = ((const float4*)src)[i];
        ushort4 u;
        u.x = f2bf(f.x); u.y = f2bf(f.y); u.z = f2bf(f.z); u.w = f2bf(f.w);
        ((ushort4*)dst)[i] = u;
    }
}

__global__ __launch_bounds__(256)
void cvt_w3(const float* __restrict__ Wq, const float* __restrict__ Wk,
            const float* __restrict__ Wv, unsigned short* __restrict__ dst)
{
    const int sel = blockIdx.y;
    const float* src = (sel == 0) ? Wq : ((sel == 1) ? Wk : Wv);
    const int i = blockIdx.x * 256 + threadIdx.x;
    float4 f = ((const float4*)src)[i];
    ushort4 u;
    u.x = f2bf(f.x); u.y = f2bf(f.y); u.z = f2bf(f.z); u.w = f2bf(f.w);
    ((ushort4*)(dst + (long)sel * DIM * DIM))[i] = u;
}

// ---------------------------------------------------------------------------
// inv_rs[row] = 1 / sum(P[row][:]) over 2048 bf16 values. 1 wave per row.
// ---------------------------------------------------------------------------
__global__ __launch_bounds__(256)
void rowsum_inv(const unsigned short* __restrict__ P, float* __restrict__ inv_rs)
{
    const int row  = blockIdx.x * 4 + (threadIdx.x >> 6);
    const int lane = threadIdx.x & 63;
    const unsigned short* pr = P + (long)row * SEQ;

    float s = 0.f;
#pragma unroll
    for (int it = 0; it < 4; ++it) {
        uint4 u = *(const uint4*)(pr + (it * 64 + lane) * 8);
        s += bfu2f(u.x & 0xffffu) + __uint_as_float(u.x & 0xffff0000u);
        s += bfu2f(u.y & 0xffffu) + __uint_as_float(u.y & 0xffff0000u);
        s += bfu2f(u.z & 0xffffu) + __uint_as_float(u.z & 0xffff0000u);
        s += bfu2f(u.w & 0xffffu) + __uint_as_float(u.w & 0xffff0000u);
    }
    for (int off = 32; off > 0; off >>= 1)
        s += __shfl_xor(s, off);
    if (lane == 0) inv_rs[row] = 1.0f / s;
}

// ---------------------------------------------------------------------------
extern "C" void kernel_launch(void* const* d_in, const int* in_sizes, int n_in,
                              void* d_out, int out_size, void* d_ws, size_t ws_size,
                              hipStream_t stream)
{
    const float* x  = (const float*)d_in[0];
    const float* Wq = (const float*)d_in[1];
    const float* bq = (const float*)d_in[2];
    const float* Wk = (const float*)d_in[3];
    const float* bk = (const float*)d_in[4];
    const float* Wv = (const float*)d_in[5];
    const float* bv = (const float*)d_in[6];
    float* out = (float*)d_out;

    // Workspace layout (>=160MB + 32KB):
    //  [0,16MB):    xb bf16 [8192][1024]
    //  [16,22MB):   Wb bf16 [3][1024][1024]
    //  [64,112MB):  qkv bf16 [8192][3072]  (V cols never written; vt instead)
    //  [112,128MB): vt  bf16 [4][1024][2048]
    //  [128,160MB): P   bf16 [4][2048][2048]  (unnormalized exp)
    //  [160MB,+32KB): inv_rs fp32 [8192]
    char* ws = (char*)d_ws;
    unsigned short* xb   = (unsigned short*)ws;
    unsigned short* Wb   = (unsigned short*)(ws + 16u * 1024 * 1024);
    unsigned short* qkv  = (unsigned short*)(ws + 64u * 1024 * 1024);
    unsigned short* vt   = (unsigned short*)(ws + 112u * 1024 * 1024);
    unsigned short* P    = (unsigned short*)(ws + 128u * 1024 * 1024);
    float*          irs  = (float*)(ws + 160u * 1024 * 1024);

    const float scale = 0.03125f;   // 1/sqrt(1024)
    dim3 blk(256);
    dim3 blk512(512);

    // 1) converts
    cvt_x<<<NTOK * DIM / 4 / 256, blk, 0, stream>>>(x, xb, NTOK * DIM / 4);
    cvt_w3<<<dim3(DIM * DIM / 4 / 256, 3), blk, 0, stream>>>(Wq, Wk, Wv, Wb);

    // 2) fused QKV projection, 128x256 tiles -> 64*12 = 768 blocks (3 exact rounds)
    gemm2<0, 1><<<dim3(NTOK / 128, NQKV / 256), blk512, 0, stream>>>(
        xb, Wb, qkv, bq, bk, bv, vt, nullptr,
        DIM, DIM, DIM, NQKV, 0, 0, 0, 1.0f);

    // 3) P[b] = exp(q[b].k[b]^T * scale), 256x256 tiles -> 8*8*4 = 256 (exact)
    gemm2<2, 2><<<dim3(SEQ / 256, SEQ / 256, 4), blk512, 0, stream>>>(
        qkv, qkv + 1024, P, nullptr, nullptr, nullptr, nullptr, nullptr,
        DIM, NQKV, NQKV, SEQ,
        (long)SEQ * NQKV, (long)SEQ * NQKV, (long)SEQ * SEQ, scale);

    // 4) inv_rs = 1 / rowsum(P)
    rowsum_inv<<<NTOK / 4, blk, 0, stream>>>(P, irs);

    // 5) out[b] = (P[b].vt[b]^T) * inv_rs, 128x256 tiles -> 16*4*4 = 256 (exact)
    gemm2<1, 1><<<dim3(SEQ / 128, DIM / 256, 4), blk512, 0, stream>>>(
        P, vt, out, nullptr, nullptr, nullptr, nullptr, irs,
        SEQ, SEQ, SEQ, DIM,
        (long)SEQ * SEQ, (long)DIM * SEQ, (long)SEQ * DIM, 1.0f);
}

// Round 6
// 248.505 us; speedup vs baseline: 1.0980x; 1.0143x over previous
//
#include <hip/hip_runtime.h>

#define SEQ  2048
#define DIM  1024
#define NTOK 8192   // 4*SEQ
#define NQKV 3072

typedef __attribute__((ext_vector_type(8))) __bf16 bf16x8;
typedef __attribute__((ext_vector_type(4))) float  f32x4;

__device__ __forceinline__ unsigned short f2bf(float f) {
    unsigned int u = __float_as_uint(f);
    u += 0x7fffu + ((u >> 16) & 1u);          // round-to-nearest-even
    return (unsigned short)(u >> 16);
}

__device__ __forceinline__ float bfu2f(unsigned int lo16) {
    return __uint_as_float(lo16 << 16);
}

__device__ __forceinline__ void load_lds_128(const unsigned short* g, unsigned short* l) {
    __builtin_amdgcn_global_load_lds(
        (const __attribute__((address_space(1))) void*)g,
        (__attribute__((address_space(3))) void*)l, 16, 0, 0);
}

#define BAR()   asm volatile("s_barrier" ::: "memory")
#define LGKM0() do { asm volatile("s_waitcnt lgkmcnt(0)" ::: "memory"); \
                     __builtin_amdgcn_sched_barrier(0); } while (0)
// counted vmcnt, last-tile variant drains fully
#define VMCNT(pf, N)                                                       \
    do { if (pf) asm volatile("s_waitcnt vmcnt(" #N ")" ::: "memory");     \
         else    asm volatile("s_waitcnt vmcnt(0)" ::: "memory"); } while (0)

// ===========================================================================
// m201-style convoy phase:  { ds_read frags | stage next half-tile | BARRIER |
// lgkmcnt(0) | setprio(1) 16 MFMA setprio(0) | counted vmcnt | BARRIER }
// The barrier BETWEEN read-issue and read-drain forms the wave convoy:
// early waves clear lgkm(0) and MFMA while later waves' reads drain ->
// LDS and MFMA pipes concurrently busy (phase ~ max, not sum).
// LDS swizzle: rows 128B, chunk slot c of row r holds global chunk
// g = c ^ (r&7) -> ds_read_b128 2-way free (SQ_LDS_BANK_CONFLICT==0, r2-r5).
// ===========================================================================

// ---------------------------------------------------------------------------
// QK^T: 256x256 tile, BK=64, 8 waves 2M x 4N (per-wave 128x64).
// Fragment row remap so half-tiles are CONTIGUOUS 128-row blocks:
//   A row = mh*128 + wm*64 + m*16 + l4   (mh = M-half, m = 0..3)
//   B row = nh*128 + wn*32 + n*16 + l4   (nh = N-half, n = 0..1)
// 4 quadrant-phases/K-tile: Q0(mh0,nh0) Q1(mh0,nh1) Q2(mh1,nh1) Q3(mh1,nh0)
// reads/phase: 12 / 4 / 8 / 4 (A or B held in regs across phases).
// Stage order (1 half-tile = 2 gloads per phase): Alo, Blo, Bhi, Ahi.
// Ledger (uniform vmcnt(4) at each phase end, 6 loads steady in flight):
//   end-ph0(t): fly {Bhi(t),Ahi(t),Alo(t+1)}  -> drains Bhi(t)  (ph1 need)
//   end-ph1(t): fly {Ahi(t),Alo,Blo(t+1)}     -> drains Ahi(t)  (ph2 need)
//   end-ph2(t): fly {Alo,Blo,Bhi(t+1)}        -> (ph3 re-reads Blo(t): done)
//   end-ph3(t): fly {Blo,Bhi,Ahi(t+1)}        -> drains Blo(t+1) (ph0 need;
//                                               Alo(t+1) drained at ph2)
// Deadline per half-tile >= 3 phases (~2000 cyc) >> HBM latency.
// ---------------------------------------------------------------------------
#define CLUS_QK(MH, NH)                                                    \
    do {                                                                   \
        __builtin_amdgcn_s_setprio(1);                                     \
        _Pragma("unroll")                                                  \
        for (int m = 0; m < 4; ++m)                                        \
            _Pragma("unroll")                                              \
            for (int n = 0; n < 2; ++n) {                                  \
                acc[MH][m][NH][n] = __builtin_amdgcn_mfma_f32_16x16x32_bf16( \
                    aR[m][0], bR[n][0], acc[MH][m][NH][n], 0, 0, 0);       \
                acc[MH][m][NH][n] = __builtin_amdgcn_mfma_f32_16x16x32_bf16( \
                    aR[m][1], bR[n][1], acc[MH][m][NH][n], 0, 0, 0);       \
            }                                                              \
        __builtin_amdgcn_s_setprio(0);                                     \
    } while (0)

__global__ __launch_bounds__(512, 2)
void gemm_qk(const unsigned short* __restrict__ A, const unsigned short* __restrict__ B,
             unsigned short* __restrict__ C,
             int K, int lda, int ldb, int ldc,
             long sA, long sB, long sC, float alpha)
{
    constexpr int AT = 256 * 64;                // 32 KB per buffer
    constexpr int BT = 256 * 64;
    __shared__ __align__(16) unsigned short As[2 * AT];   // 64 KB
    __shared__ __align__(16) unsigned short Bs[2 * BT];   // 64 KB

    const int tid  = threadIdx.x;               // 512 thr = 8 waves
    const int wave = tid >> 6;
    const int lane = tid & 63;
    const int l4   = lane & 15;
    const int lh   = lane >> 4;
    const int wm   = wave >> 2;                 // 0..1
    const int wn   = wave & 3;                  // 0..3

    const int m0 = blockIdx.x * 256;
    const int n0 = blockIdx.y * 256;
    const int z  = blockIdx.z;
    A += (long)z * sA;
    B += (long)z * sB;

    const int r0 = tid >> 3;                    // 0..63
    const int gc = (tid & 7) ^ (r0 & 7);
    const unsigned short* Ag = A + (long)(m0 + r0) * lda + gc * 8;
    const unsigned short* Bg = B + (long)(n0 + r0) * ldb + gc * 8;
    unsigned short* Al = As + tid * 8;
    unsigned short* Bl = Bs + tid * 8;

    const int NT = K >> 6;

    auto stA = [&](int t, int u, int half) {    // 2 gloads: rows half*128..+127
        const long kof = (long)t * 64;
        load_lds_128(Ag + kof + (long)(64 * (2 * half + 0)) * lda, Al + u * AT + (2 * half + 0) * 4096);
        load_lds_128(Ag + kof + (long)(64 * (2 * half + 1)) * lda, Al + u * AT + (2 * half + 1) * 4096);
    };
    auto stB = [&](int t, int u, int half) {
        const long kof = (long)t * 64;
        load_lds_128(Bg + kof + (long)(64 * (2 * half + 0)) * ldb, Bl + u * BT + (2 * half + 0) * 4096);
        load_lds_128(Bg + kof + (long)(64 * (2 * half + 1)) * ldb, Bl + u * BT + (2 * half + 1) * 4096);
    };

    const int aoff = (wm * 64 + l4) * 64;       // + mh*8192 + m*1024 + cs
    const int boff = (wn * 32 + l4) * 64;       // + nh*8192 + n*1024 + cs
    const int cs0  = (lh ^ (lane & 7)) * 8;
    const int cs1  = ((4 + lh) ^ (lane & 7)) * 8;

    f32x4 acc[2][4][2][2] = {};
    bf16x8 aR[4][2], bR[2][2];

    auto rdA = [&](const unsigned short* Ab, int mh) {
#pragma unroll
        for (int m = 0; m < 4; ++m) {
            aR[m][0] = *(const bf16x8*)(Ab + mh * 8192 + m * 1024 + cs0);
            aR[m][1] = *(const bf16x8*)(Ab + mh * 8192 + m * 1024 + cs1);
        }
    };
    auto rdB = [&](const unsigned short* Bb, int nh) {
#pragma unroll
        for (int n = 0; n < 2; ++n) {
            bR[n][0] = *(const bf16x8*)(Bb + nh * 8192 + n * 1024 + cs0);
            bR[n][1] = *(const bf16x8*)(Bb + nh * 8192 + n * 1024 + cs1);
        }
    };

    // prologue: issue order = FIFO order: Alo, Blo, Bhi, Ahi of tile 0
    stA(0, 0, 0); stB(0, 0, 0); stB(0, 0, 1); stA(0, 0, 1);
    asm volatile("s_waitcnt vmcnt(4)" ::: "memory");    // drain Alo,Blo
    BAR();

    for (int t = 0; t < NT; ++t) {
        const int u  = t & 1;
        const int pf = (t + 1 < NT);
        const unsigned short* Ab = As + u * AT + aoff;
        const unsigned short* Bb = Bs + u * BT + boff;

        // ---- ph0: Q(mh0, nh0) ----
        rdA(Ab, 0); rdB(Bb, 0);
        if (pf) stA(t + 1, u ^ 1, 0);
        BAR(); LGKM0();
        CLUS_QK(0, 0);
        VMCNT(pf, 4); BAR();

        // ---- ph1: Q(mh0, nh1) ----
        rdB(Bb, 1);
        if (pf) stB(t + 1, u ^ 1, 0);
        BAR(); LGKM0();
        CLUS_QK(0, 1);
        VMCNT(pf, 4); BAR();

        // ---- ph2: Q(mh1, nh1) ----
        rdA(Ab, 1);
        if (pf) stB(t + 1, u ^ 1, 1);
        BAR(); LGKM0();
        CLUS_QK(1, 1);
        VMCNT(pf, 4); BAR();

        // ---- ph3: Q(mh1, nh0) ----
        rdB(Bb, 0);
        if (pf) stA(t + 1, u ^ 1, 1);
        BAR(); LGKM0();
        CLUS_QK(1, 0);
        VMCNT(pf, 4); BAR();
    }

    // epilogue: P = exp(acc * alpha), bf16
    unsigned short* C16 = C + (long)z * sC;
#pragma unroll
    for (int mh = 0; mh < 2; ++mh)
#pragma unroll
        for (int m = 0; m < 4; ++m) {
            const int rowb = m0 + mh * 128 + wm * 64 + m * 16 + lh * 4;
#pragma unroll
            for (int nh = 0; nh < 2; ++nh)
#pragma unroll
                for (int n = 0; n < 2; ++n) {
                    const int col = n0 + nh * 128 + wn * 32 + n * 16 + l4;
#pragma unroll
                    for (int r = 0; r < 4; ++r)
                        C16[(long)(rowb + r) * ldc + col] =
                            f2bf(__expf(acc[mh][m][nh][n][r] * alpha));
                }
        }
}

// ---------------------------------------------------------------------------
// QKV / PV: 256x128 tile, BK=64, 8 waves 4M x 2N (per-wave 64x64).
// Row remap: A row = mh*128 + wm*32 + m*16 + l4 (m=0..1); B row = wn*64+n*16+l4.
// 2 convoy-phases/K-tile: ph0 = mh0 (reads A-lo 4 + B-all 8), ph1 = mh1 (A-hi 4).
// Stage: ph0 -> {Alo(t+1) 2, B(t+1) 2}; ph1 -> {Ahi(t+1) 2}.
// Ledger: end-ph0(t): fly {Ahi(t),Alo(t+1),B(t+1)} -> vmcnt(4) drains Ahi(t);
//         end-ph1(t): fly {Alo,B,Ahi(t+1)}         -> vmcnt(2) drains Alo,B.
// MODE 0: fused QKV epilogue (q,k bf16 + bias; v transposed into vt + bias)
// MODE 1: fp32 C = acc * inv_rs[row]
// ---------------------------------------------------------------------------
#define CLUS_MN(MH)                                                        \
    do {                                                                   \
        __builtin_amdgcn_s_setprio(1);                                     \
        _Pragma("unroll")                                                  \
        for (int m = 0; m < 2; ++m)                                        \
            _Pragma("unroll")                                              \
            for (int n = 0; n < 4; ++n) {                                  \
                acc[MH][m][n] = __builtin_amdgcn_mfma_f32_16x16x32_bf16(   \
                    aR[m][0], bR[n][0], acc[MH][m][n], 0, 0, 0);           \
                acc[MH][m][n] = __builtin_amdgcn_mfma_f32_16x16x32_bf16(   \
                    aR[m][1], bR[n][1], acc[MH][m][n], 0, 0, 0);           \
            }                                                              \
        __builtin_amdgcn_s_setprio(0);                                     \
    } while (0)

template <int MODE>
__global__ __launch_bounds__(512, 2)
void gemm_mn(const unsigned short* __restrict__ A, const unsigned short* __restrict__ B,
             void* __restrict__ Cv,
             const float* __restrict__ b0v, const float* __restrict__ b1v,
             const float* __restrict__ b2v, unsigned short* __restrict__ vt,
             const float* __restrict__ inv_rs,
             int K, int lda, int ldb, int ldc,
             long sA, long sB, long sC)
{
    constexpr int AT = 256 * 64;                // 32 KB
    constexpr int BT = 128 * 64;                // 16 KB
    __shared__ __align__(16) unsigned short As[2 * AT];   // 64 KB
    __shared__ __align__(16) unsigned short Bs[2 * BT];   // 32 KB

    const int tid  = threadIdx.x;
    const int wave = tid >> 6;
    const int lane = tid & 63;
    const int l4   = lane & 15;
    const int lh   = lane >> 4;
    const int wm   = wave >> 1;                 // 0..3
    const int wn   = wave & 1;                  // 0..1

    const int m0 = blockIdx.x * 256;
    const int n0 = blockIdx.y * 128;
    const int z  = blockIdx.z;
    A += (long)z * sA;
    B += (long)z * sB;

    const int r0 = tid >> 3;
    const int gc = (tid & 7) ^ (r0 & 7);
    const unsigned short* Ag = A + (long)(m0 + r0) * lda + gc * 8;
    const unsigned short* Bg = B + (long)(n0 + r0) * ldb + gc * 8;
    unsigned short* Al = As + tid * 8;
    unsigned short* Bl = Bs + tid * 8;

    const int NT = K >> 6;

    auto stA = [&](int t, int u, int half) {
        const long kof = (long)t * 64;
        load_lds_128(Ag + kof + (long)(64 * (2 * half + 0)) * lda, Al + u * AT + (2 * half + 0) * 4096);
        load_lds_128(Ag + kof + (long)(64 * (2 * half + 1)) * lda, Al + u * AT + (2 * half + 1) * 4096);
    };
    auto stB = [&](int t, int u) {
        const long kof = (long)t * 64;
        load_lds_128(Bg + kof,                    Bl + u * BT);
        load_lds_128(Bg + kof + (long)64 * ldb,   Bl + u * BT + 4096);
    };

    const int aoff = (wm * 32 + l4) * 64;       // + mh*8192 + m*1024 + cs
    const int boff = (wn * 64 + l4) * 64;       // + n*1024 + cs
    const int cs0  = (lh ^ (lane & 7)) * 8;
    const int cs1  = ((4 + lh) ^ (lane & 7)) * 8;

    f32x4 acc[2][2][4] = {};
    bf16x8 aR[2][2], bR[4][2];

    auto rdA = [&](const unsigned short* Ab, int mh) {
#pragma unroll
        for (int m = 0; m < 2; ++m) {
            aR[m][0] = *(const bf16x8*)(Ab + mh * 8192 + m * 1024 + cs0);
            aR[m][1] = *(const bf16x8*)(Ab + mh * 8192 + m * 1024 + cs1);
        }
    };
    auto rdB = [&](const unsigned short* Bb) {
#pragma unroll
        for (int n = 0; n < 4; ++n) {
            bR[n][0] = *(const bf16x8*)(Bb + n * 1024 + cs0);
            bR[n][1] = *(const bf16x8*)(Bb + n * 1024 + cs1);
        }
    };

    // prologue: FIFO order Alo, B, Ahi of tile 0
    stA(0, 0, 0); stB(0, 0); stA(0, 0, 1);
    asm volatile("s_waitcnt vmcnt(2)" ::: "memory");    // drain Alo, B
    BAR();

    for (int t = 0; t < NT; ++t) {
        const int u  = t & 1;
        const int pf = (t + 1 < NT);
        const unsigned short* Ab = As + u * AT + aoff;
        const unsigned short* Bb = Bs + u * BT + boff;

        // ---- ph0: mh = 0 ----
        rdA(Ab, 0); rdB(Bb);
        if (pf) { stA(t + 1, u ^ 1, 0); stB(t + 1, u ^ 1); }
        BAR(); LGKM0();
        CLUS_MN(0);
        VMCNT(pf, 4); BAR();

        // ---- ph1: mh = 1 ----
        rdA(Ab, 1);
        if (pf) stA(t + 1, u ^ 1, 1);
        BAR(); LGKM0();
        CLUS_MN(1);
        VMCNT(pf, 2); BAR();
    }

    // ---- epilogue ----
    // C/D 16x16x32: col = l4 (+n*16), row = lh*4 + r (+m*16 +mh*128 +wm*32)
    if (MODE == 0) {
        if (n0 >= 2048) {
            // V columns -> vt[b][d][m] (+bias), packed 4-m ushort4 stores
#pragma unroll
            for (int n = 0; n < 4; ++n) {
                const int d = n0 + wn * 64 + n * 16 + l4 - 2048;
                const float bias = b2v[d];
#pragma unroll
                for (int mh = 0; mh < 2; ++mh)
#pragma unroll
                    for (int m = 0; m < 2; ++m) {
                        const int row = m0 + mh * 128 + wm * 32 + m * 16 + lh * 4;
                        const int bb = row >> 11;
                        const int mm = row & 2047;
                        ushort4 uu;
                        uu.x = f2bf(acc[mh][m][n][0] + bias);
                        uu.y = f2bf(acc[mh][m][n][1] + bias);
                        uu.z = f2bf(acc[mh][m][n][2] + bias);
                        uu.w = f2bf(acc[mh][m][n][3] + bias);
                        *(ushort4*)(vt + ((long)bb * DIM + d) * SEQ + mm) = uu;
                    }
            }
        } else {
            unsigned short* C16 = (unsigned short*)Cv;
#pragma unroll
            for (int n = 0; n < 4; ++n) {
                const int col = n0 + wn * 64 + n * 16 + l4;
                const float bias = (col >= 1024) ? b1v[col - 1024] : b0v[col];
#pragma unroll
                for (int mh = 0; mh < 2; ++mh)
#pragma unroll
                    for (int m = 0; m < 2; ++m) {
                        const int rowb = m0 + mh * 128 + wm * 32 + m * 16 + lh * 4;
#pragma unroll
                        for (int r = 0; r < 4; ++r)
                            C16[(long)(rowb + r) * ldc + col] =
                                f2bf(acc[mh][m][n][r] + bias);
                    }
            }
        }
    } else {  // MODE 1: fp32 C = acc * inv_rs[row]
        float* C = (float*)Cv + (long)z * sC;
        const float* ir = inv_rs + (long)z * SEQ;
#pragma unroll
        for (int mh = 0; mh < 2; ++mh)
#pragma unroll
            for (int m = 0; m < 2; ++m) {
                const int rowb = m0 + mh * 128 + wm * 32 + m * 16 + lh * 4;
                const float4 inv4 = *(const float4*)(ir + rowb);
#pragma unroll
                for (int n = 0; n < 4; ++n) {
                    const int col = n0 + wn * 64 + n * 16 + l4;
                    C[(long)(rowb + 0) * ldc + col] = acc[mh][m][n][0] * inv4.x;
                    C[(long)(rowb + 1) * ldc + col] = acc[mh][m][n][1] * inv4.y;
                    C[(long)(rowb + 2) * ldc + col] = acc[mh][m][n][2] * inv4.z;
                    C[(long)(rowb + 3) * ldc + col] = acc[mh][m][n][3] * inv4.w;
                }
            }
    }
}

// ---------------------------------------------------------------------------
__global__ __launch_bounds__(256)
void cvt_x(const float* __restrict__ src, unsigned short* __restrict__ dst, int n4)
{
    int i = blockIdx.x * 256 + threadIdx.x;
    if (i < n4) {
        float4 f = ((const float4*)src)[i];
        ushort4 u;
        u.x = f2bf(f.x); u.y = f2bf(f.y); u.z = f2bf(f.z); u.w = f2bf(f.w);
        ((ushort4*)dst)[i] = u;
    }
}

__global__ __launch_bounds__(256)
void cvt_w3(const float* __restrict__ Wq, const float* __restrict__ Wk,
            const float* __restrict__ Wv, unsigned short* __restrict__ dst)
{
    const int sel = blockIdx.y;
    const float* src = (sel == 0) ? Wq : ((sel == 1) ? Wk : Wv);
    const int i = blockIdx.x * 256 + threadIdx.x;
    float4 f = ((const float4*)src)[i];
    ushort4 u;
    u.x = f2bf(f.x); u.y = f2bf(f.y); u.z = f2bf(f.z); u.w = f2bf(f.w);
    ((ushort4*)(dst + (long)sel * DIM * DIM))[i] = u;
}

// ---------------------------------------------------------------------------
// inv_rs[row] = 1 / sum(P[row][:]) over 2048 bf16 values. 1 wave per row.
// ---------------------------------------------------------------------------
__global__ __launch_bounds__(256)
void rowsum_inv(const unsigned short* __restrict__ P, float* __restrict__ inv_rs)
{
    const int row  = blockIdx.x * 4 + (threadIdx.x >> 6);
    const int lane = threadIdx.x & 63;
    const unsigned short* pr = P + (long)row * SEQ;

    float s = 0.f;
#pragma unroll
    for (int it = 0; it < 4; ++it) {
        uint4 u = *(const uint4*)(pr + (it * 64 + lane) * 8);
        s += bfu2f(u.x & 0xffffu) + __uint_as_float(u.x & 0xffff0000u);
        s += bfu2f(u.y & 0xffffu) + __uint_as_float(u.y & 0xffff0000u);
        s += bfu2f(u.z & 0xffffu) + __uint_as_float(u.z & 0xffff0000u);
        s += bfu2f(u.w & 0xffffu) + __uint_as_float(u.w & 0xffff0000u);
    }
    for (int off = 32; off > 0; off >>= 1)
        s += __shfl_xor(s, off);
    if (lane == 0) inv_rs[row] = 1.0f / s;
}

// ---------------------------------------------------------------------------
extern "C" void kernel_launch(void* const* d_in, const int* in_sizes, int n_in,
                              void* d_out, int out_size, void* d_ws, size_t ws_size,
                              hipStream_t stream)
{
    const float* x  = (const float*)d_in[0];
    const float* Wq = (const float*)d_in[1];
    const float* bq = (const float*)d_in[2];
    const float* Wk = (const float*)d_in[3];
    const float* bk = (const float*)d_in[4];
    const float* Wv = (const float*)d_in[5];
    const float* bv = (const float*)d_in[6];
    float* out = (float*)d_out;

    // Workspace layout (>=160MB + 32KB):
    //  [0,16MB):    xb bf16 [8192][1024]
    //  [16,22MB):   Wb bf16 [3][1024][1024]
    //  [64,112MB):  qkv bf16 [8192][3072]  (V cols never written; vt instead)
    //  [112,128MB): vt  bf16 [4][1024][2048]
    //  [128,160MB): P   bf16 [4][2048][2048]  (unnormalized exp)
    //  [160MB,+32KB): inv_rs fp32 [8192]
    char* ws = (char*)d_ws;
    unsigned short* xb   = (unsigned short*)ws;
    unsigned short* Wb   = (unsigned short*)(ws + 16u * 1024 * 1024);
    unsigned short* qkv  = (unsigned short*)(ws + 64u * 1024 * 1024);
    unsigned short* vt   = (unsigned short*)(ws + 112u * 1024 * 1024);
    unsigned short* P    = (unsigned short*)(ws + 128u * 1024 * 1024);
    float*          irs  = (float*)(ws + 160u * 1024 * 1024);

    const float scale = 0.03125f;   // 1/sqrt(1024)
    dim3 blk(256);
    dim3 blk512(512);

    // 1) converts
    cvt_x<<<NTOK * DIM / 4 / 256, blk, 0, stream>>>(x, xb, NTOK * DIM / 4);
    cvt_w3<<<dim3(DIM * DIM / 4 / 256, 3), blk, 0, stream>>>(Wq, Wk, Wv, Wb);

    // 2) fused QKV projection, 256x128 tiles -> 32*24 = 768 blocks (3 exact)
    gemm_mn<0><<<dim3(NTOK / 256, NQKV / 128), blk512, 0, stream>>>(
        xb, Wb, qkv, bq, bk, bv, vt, nullptr,
        DIM, DIM, DIM, NQKV, 0, 0, 0);

    // 3) P[b] = exp(q[b].k[b]^T * scale), 256x256 tiles -> 8*8*4 = 256 (exact)
    gemm_qk<<<dim3(SEQ / 256, SEQ / 256, 4), blk512, 0, stream>>>(
        qkv, qkv + 1024, P,
        DIM, NQKV, NQKV, SEQ,
        (long)SEQ * NQKV, (long)SEQ * NQKV, (long)SEQ * SEQ, scale);

    // 4) inv_rs = 1 / rowsum(P)
    rowsum_inv<<<NTOK / 4, blk, 0, stream>>>(P, irs);

    // 5) out[b] = (P[b].vt[b]^T) * inv_rs, 256x128 tiles -> 8*8*4 = 256 (exact)
    gemm_mn<1><<<dim3(SEQ / 256, DIM / 128, 4), blk512, 0, stream>>>(
        P, vt, out, nullptr, nullptr, nullptr, nullptr, irs,
        SEQ, SEQ, SEQ, DIM,
        (long)SEQ * SEQ, (long)DIM * SEQ, (long)SEQ * DIM);
}